// Round 4
// baseline (593.628 us; speedup 1.0000x reference)
//
#include <hip/hip_runtime.h>
#include <hip/hip_bf16.h>

#define N_DRUG 20000
#define N_DIS  40000
#define NE     500000
#define D      128

typedef __hip_bfloat16 bf16;

__device__ __forceinline__ float b2f(bf16 x) { return __bfloat162float(x); }

// Wh(bf16) = feat @ W + b ; s1 = Wh_f32 . a1 ; s2 = Wh_f32 . a2 (per-row scalars)
// Inputs feat/W/bias/a are float32. block = 256 threads = 2 rows x 128 cols.
__global__ void k_gemm(const float* __restrict__ feat, const float* __restrict__ W,
                       const float* __restrict__ bias, const float* __restrict__ a1,
                       const float* __restrict__ a2, bf16* __restrict__ Wh,
                       float* __restrict__ s1, float* __restrict__ s2, int M)
{
    const int tid = threadIdx.x;
    const int ty  = tid >> 7;       // row within block
    const int n   = tid & 127;      // output column
    const int row = blockIdx.x * 2 + ty;
    __shared__ float fs[2][128];
    __shared__ float red[2][2][2];  // [ty][wave-in-row][p1/p2]

    fs[ty][n] = feat[(size_t)row * D + n];
    __syncthreads();

    float acc = bias[n];
    const float* Wcol = W + n;
#pragma unroll 8
    for (int k = 0; k < D; ++k)
        acc += fs[ty][k] * Wcol[(size_t)k * D];

    Wh[(size_t)row * D + n] = __float2bfloat16(acc);

    float p1 = acc * a1[n];
    float p2 = acc * a2[n];
#pragma unroll
    for (int off = 32; off; off >>= 1) {
        p1 += __shfl_down(p1, off);
        p2 += __shfl_down(p2, off);
    }
    const int lane = tid & 63;
    const int wir  = n >> 6;
    if (lane == 0) { red[ty][wir][0] = p1; red[ty][wir][1] = p2; }
    __syncthreads();
    if (n == 0) {
        s1[row] = red[ty][0][0] + red[ty][1][0];
        s2[row] = red[ty][0][1] + red[ty][1][1];
    }
}

__global__ void k_hist(const int* __restrict__ dst, int* __restrict__ cnt)
{
    int i = blockIdx.x * blockDim.x + threadIdx.x;
    if (i < NE) atomicAdd(&cnt[dst[i]], 1);
}

// Assign each dst node a contiguous segment [base, base+cnt): block-local
// inclusive scan + one atomicAdd per block (segment order is arbitrary).
__global__ void k_base(const int* __restrict__ cnt, int* __restrict__ base,
                       int* __restrict__ cursor, int* __restrict__ total, int n)
{
    __shared__ int sd[256];
    __shared__ int sbase;
    const int tid = threadIdx.x;
    const int gid = blockIdx.x * 256 + tid;
    int c = (gid < n) ? cnt[gid] : 0;
    sd[tid] = c;
    __syncthreads();
    for (int off = 1; off < 256; off <<= 1) {
        int v = (tid >= off) ? sd[tid - off] : 0;
        __syncthreads();
        sd[tid] += v;
        __syncthreads();
    }
    if (tid == 255) sbase = atomicAdd(total, sd[255]);
    __syncthreads();
    if (gid < n) {
        int b = sbase + sd[tid] - c;
        base[gid]   = b;
        cursor[gid] = b;
    }
}

// Scatter src-id into the dst node's CSR segment (order within segment arbitrary).
__global__ void k_fill(const int* __restrict__ src, const int* __restrict__ dst,
                       int* __restrict__ cursor, int* __restrict__ col)
{
    int i = blockIdx.x * blockDim.x + threadIdx.x;
    if (i >= NE) return;
    int pos = atomicAdd(&cursor[dst[i]], 1);
    col[pos] = src[i];
}

// One wave per dst node. Batched: 64 edges' (col, ex) loaded lane-parallel,
// then broadcast with __shfl. Unnormalized accumulate; divide by denom at end.
// Each lane owns 2 output dims (float2 at 2*lane). f32 output.
__global__ void k_agg(const int* __restrict__ base, const int* __restrict__ cnt,
                      const int* __restrict__ col, const float* __restrict__ ssrc,
                      const float* __restrict__ sdst_arr, const bf16* __restrict__ Whs,
                      const float* __restrict__ addend, float* __restrict__ out, int n)
{
    const int gw   = (int)((blockIdx.x * blockDim.x + threadIdx.x) >> 6);
    const int lane = threadIdx.x & 63;
    if (gw >= n) return;
    const int b = base[gw], c = cnt[gw];
    const float sd = sdst_arr[gw];

    float ax = 0.f, ay = 0.f, dpart = 0.f;
    for (int t0 = 0; t0 < c; t0 += 64) {
        const int rem = c - t0;
        const int k = rem < 64 ? rem : 64;
        int myc = 0; float myex = 0.f;
        if (lane < k) {
            myc = col[b + t0 + lane];
            float e = ssrc[myc] + sd;
            e = (e >= 0.f) ? e : 0.01f * e;
            e = fminf(fmaxf(e, -30.f), 30.f);  // safety clamp; inactive for sane data
            myex = __expf(e);
        }
        dpart += myex;
        for (int j = 0; j < k; ++j) {
            int   s   = __shfl(myc, j);
            float exv = __shfl(myex, j);
            __hip_bfloat162 w = *(const __hip_bfloat162*)(Whs + (size_t)s * D + 2 * lane);
            ax += exv * __bfloat162float(w.x);
            ay += exv * __bfloat162float(w.y);
        }
    }
    float denom = dpart;
#pragma unroll
    for (int off = 32; off; off >>= 1) denom += __shfl_xor(denom, off);
    const float inv = (c > 0) ? 1.f / denom : 0.f;
    ax *= inv; ay *= inv;

    size_t idx = (size_t)gw * D + 2 * lane;
    if (addend) { ax += addend[idx]; ay += addend[idx + 1]; }
    *(float2*)(out + idx) = make_float2(ax, ay);
}

extern "C" void kernel_launch(void* const* d_in, const int* in_sizes, int n_in,
                              void* d_out, int out_size, void* d_ws, size_t ws_size,
                              hipStream_t stream)
{
    const float* feat_drug = (const float*)d_in[0];
    const float* feat_dis  = (const float*)d_in[1];
    const int*   src_ind   = (const int*)d_in[2];
    const int*   dst_ind   = (const int*)d_in[3];
    const int*   src_rev   = (const int*)d_in[4];
    const int*   dst_rev   = (const int*)d_in[5];
    const int*   src_dd    = (const int*)d_in[6];
    const int*   dst_dd    = (const int*)d_in[7];
    const float* W_ind     = (const float*)d_in[8];
    const float* b_ind     = (const float*)d_in[9];
    const float* W_rev     = (const float*)d_in[10];
    const float* b_rev     = (const float*)d_in[11];
    const float* W_dd      = (const float*)d_in[12];
    const float* b_dd      = (const float*)d_in[13];
    const float* a_ind     = (const float*)d_in[14];
    const float* a_rev     = (const float*)d_in[15];
    const float* a_dd      = (const float*)d_in[16];

    float* out_drug = (float*)d_out;                        // [N_DRUG, D] f32
    float* out_dis  = (float*)d_out + (size_t)N_DRUG * D;   // [N_DIS, D]  f32

    char* ws = (char*)d_ws;
    size_t off = 0;
    auto alloc = [&](size_t bytes) -> void* {
        void* p = ws + off;
        off += (bytes + 255) & ~(size_t)255;
        return p;
    };

    // total ws usage ~34 MB
    bf16* Wh_ind = (bf16*)alloc(sizeof(bf16) * (size_t)N_DRUG * D);
    bf16* Wh_rev = (bf16*)alloc(sizeof(bf16) * (size_t)N_DIS * D);
    bf16* Wh_dd  = (bf16*)alloc(sizeof(bf16) * (size_t)N_DIS * D);

    float* s_src_ind = (float*)alloc(sizeof(float) * N_DRUG);  // Wh_ind . a_ind[:D]
    float* s_dst_rev = (float*)alloc(sizeof(float) * N_DRUG);  // Wh_ind . a_rev[D:]
    float* s_src_rev = (float*)alloc(sizeof(float) * N_DIS);   // Wh_rev . a_rev[:D]
    float* s_dst_ind = (float*)alloc(sizeof(float) * N_DIS);   // Wh_rev . a_ind[D:]
    float* s_src_dd  = (float*)alloc(sizeof(float) * N_DIS);   // Wh_dd  . a_dd[:D]
    float* s_dst_dd  = (float*)alloc(sizeof(float) * N_DIS);   // Wh_dd  . a_dd[D:]

    int* col_ind = (int*)alloc(sizeof(int) * NE);
    int* col_rev = (int*)alloc(sizeof(int) * NE);
    int* col_dd  = (int*)alloc(sizeof(int) * NE);

    int* base_ind   = (int*)alloc(sizeof(int) * N_DIS);
    int* cursor_ind = (int*)alloc(sizeof(int) * N_DIS);
    int* base_rev   = (int*)alloc(sizeof(int) * N_DRUG);
    int* cursor_rev = (int*)alloc(sizeof(int) * N_DRUG);
    int* base_dd    = (int*)alloc(sizeof(int) * N_DIS);
    int* cursor_dd  = (int*)alloc(sizeof(int) * N_DIS);

    // zero region: cnt_ind | cnt_dd | cnt_rev | totals(4)
    const size_t nzero = (size_t)N_DIS + N_DIS + N_DRUG + 4;
    int* zr = (int*)alloc(sizeof(int) * nzero);
    int* cnt_ind = zr;
    int* cnt_dd  = zr + N_DIS;
    int* cnt_rev = zr + 2 * N_DIS;
    int* totals  = zr + 2 * N_DIS + N_DRUG;  // [ind, rev, dd, pad]

    hipMemsetAsync(zr, 0, sizeof(int) * nzero, stream);

    // --- projections + per-node attention scalars ---
    k_gemm<<<N_DRUG / 2, 256, 0, stream>>>(feat_drug, W_ind, b_ind, a_ind, a_rev + D,
                                           Wh_ind, s_src_ind, s_dst_rev, N_DRUG);
    k_gemm<<<N_DIS / 2, 256, 0, stream>>>(feat_dis, W_rev, b_rev, a_rev, a_ind + D,
                                          Wh_rev, s_src_rev, s_dst_ind, N_DIS);
    k_gemm<<<N_DIS / 2, 256, 0, stream>>>(feat_dis, W_dd, b_dd, a_dd, a_dd + D,
                                          Wh_dd, s_src_dd, s_dst_dd, N_DIS);

    const int EB = (NE + 255) / 256;

    // --- CSR build: histogram -> base alloc -> fill ---
    k_hist<<<EB, 256, 0, stream>>>(dst_ind, cnt_ind);
    k_hist<<<EB, 256, 0, stream>>>(dst_rev, cnt_rev);
    k_hist<<<EB, 256, 0, stream>>>(dst_dd, cnt_dd);

    k_base<<<(N_DIS + 255) / 256, 256, 0, stream>>>(cnt_ind, base_ind, cursor_ind, &totals[0], N_DIS);
    k_base<<<(N_DRUG + 255) / 256, 256, 0, stream>>>(cnt_rev, base_rev, cursor_rev, &totals[1], N_DRUG);
    k_base<<<(N_DIS + 255) / 256, 256, 0, stream>>>(cnt_dd, base_dd, cursor_dd, &totals[2], N_DIS);

    k_fill<<<EB, 256, 0, stream>>>(src_ind, dst_ind, cursor_ind, col_ind);
    k_fill<<<EB, 256, 0, stream>>>(src_rev, dst_rev, cursor_rev, col_rev);
    k_fill<<<EB, 256, 0, stream>>>(src_dd, dst_dd, cursor_dd, col_dd);

    // --- gather-based softmax aggregation (one wave per dst node) ---
    // indication -> out_dis (f32)
    k_agg<<<(N_DIS + 3) / 4, 256, 0, stream>>>(base_ind, cnt_ind, col_ind,
                                               s_src_ind, s_dst_ind, Wh_ind,
                                               nullptr, out_dis, N_DIS);
    // dd, adding out_dis in place -> final h_dis
    k_agg<<<(N_DIS + 3) / 4, 256, 0, stream>>>(base_dd, cnt_dd, col_dd,
                                               s_src_dd, s_dst_dd, Wh_dd,
                                               out_dis, out_dis, N_DIS);
    // rev_indication -> h_drug
    k_agg<<<(N_DRUG + 3) / 4, 256, 0, stream>>>(base_rev, cnt_rev, col_rev,
                                                s_src_rev, s_dst_rev, Wh_rev,
                                                nullptr, out_drug, N_DRUG);
}

// Round 5
// 408.372 us; speedup vs baseline: 1.4536x; 1.4536x over previous
//
#include <hip/hip_runtime.h>
#include <hip/hip_bf16.h>

#define N_DRUG 20000
#define N_DIS  40000
#define NE     500000
#define D      128
#define PITCH  136   // bf16 elems per LDS row: 272 B = 17*16 (16B-aligned, bank-stride 4 -> 2-way, free)

typedef __hip_bfloat16 bf16;
typedef __attribute__((ext_vector_type(8))) short short8;
typedef __attribute__((ext_vector_type(4))) float floatx4;

__device__ __forceinline__ float b2f(bf16 x) { return __bfloat162float(x); }

// MFMA GEMM: Wh(bf16) = feat(f32->bf16) @ W(f32->bf16) + b, plus per-row scalars
// s1 = Wh . a1, s2 = Wh . a2. Block = 256 thr (4 waves) = 64 rows x 128 cols.
// mfma_f32_16x16x32_bf16: A lane l -> A[l&15][(l>>4)*8+j]; B lane l -> B[(l>>4)*8+j][l&15];
// C/D lane l, reg r -> row (l>>4)*4+r, col l&15  (m89/m91-verified).
__global__ void k_gemm_mfma(const float* __restrict__ feat, int M,
                            const float* __restrict__ W, const float* __restrict__ bias,
                            const float* __restrict__ a1, const float* __restrict__ a2,
                            bf16* __restrict__ Wh, float* __restrict__ s1,
                            float* __restrict__ s2)
{
    __shared__ __align__(16) bf16 WT[128 * PITCH];  // WT[n][k] = W[k][n]
    __shared__ __align__(16) bf16 FS[64 * PITCH];   // FS[r][k] = feat[row0+r][k]
    const int tid  = threadIdx.x;
    const int row0 = blockIdx.x * 64;

    // stage W (64 KB f32, L2-hot) -> transposed bf16 in LDS
#pragma unroll 4
    for (int rep = 0; rep < 64; ++rep) {
        int idx = rep * 256 + tid;           // k*128+n, coalesced read
        int k = idx >> 7, n = idx & 127;
        WT[n * PITCH + k] = __float2bfloat16(W[idx]);
    }
    // stage 64 feat rows -> bf16 in LDS (row-major, contiguous writes)
#pragma unroll 4
    for (int rep = 0; rep < 32; ++rep) {
        int idx = rep * 256 + tid;           // r*128+k
        int r = idx >> 7, k = idx & 127;
        int gr = row0 + r;
        float v = (gr < M) ? feat[(size_t)gr * D + k] : 0.f;
        FS[r * PITCH + k] = __float2bfloat16(v);
    }
    __syncthreads();

    const int wave = tid >> 6;          // 0..3 -> rows wave*16..+15
    const int lane = tid & 63;
    const int m0   = wave * 16;
    const int arow = lane & 15;
    const int kq   = lane >> 4;         // quad 0..3

    floatx4 acc[8];
#pragma unroll
    for (int t = 0; t < 8; ++t) acc[t] = (floatx4){0.f, 0.f, 0.f, 0.f};

#pragma unroll
    for (int ks = 0; ks < 4; ++ks) {
        const int kb = ks * 32 + kq * 8;
        short8 afrag = *(const short8*)(FS + (m0 + arow) * PITCH + kb);
#pragma unroll
        for (int t = 0; t < 8; ++t) {
            short8 bfrag = *(const short8*)(WT + (t * 16 + arow) * PITCH + kb);
            acc[t] = __builtin_amdgcn_mfma_f32_16x16x32_bf16(afrag, bfrag, acc[t], 0, 0, 0);
        }
    }

    // epilogue: bias add, Wh store, fused s1/s2 partial dots
    const int crow = m0 + kq * 4;       // + r
    float p1[4] = {0.f, 0.f, 0.f, 0.f};
    float p2[4] = {0.f, 0.f, 0.f, 0.f};
#pragma unroll
    for (int t = 0; t < 8; ++t) {
        const int n = t * 16 + arow;
        const float bn = bias[n], a1n = a1[n], a2n = a2[n];
#pragma unroll
        for (int r = 0; r < 4; ++r) {
            float v = acc[t][r] + bn;
            int gr = row0 + crow + r;
            if (gr < M) Wh[(size_t)gr * D + n] = __float2bfloat16(v);
            p1[r] += v * a1n;
            p2[r] += v * a2n;
        }
    }
    // reduce across the 16 lanes of this quad (xor bits 0..3 stay in-quad)
#pragma unroll
    for (int r = 0; r < 4; ++r) {
#pragma unroll
        for (int off = 1; off < 16; off <<= 1) {
            p1[r] += __shfl_xor(p1[r], off);
            p2[r] += __shfl_xor(p2[r], off);
        }
    }
    if (arow == 0) {
#pragma unroll
        for (int r = 0; r < 4; ++r) {
            int gr = row0 + crow + r;
            if (gr < M) { s1[gr] = p1[r]; s2[gr] = p2[r]; }
        }
    }
}

__global__ void k_hist(const int* __restrict__ dst, int* __restrict__ cnt)
{
    int i = blockIdx.x * blockDim.x + threadIdx.x;
    if (i < NE) atomicAdd(&cnt[dst[i]], 1);
}

// Assign each dst node a contiguous segment [base, base+cnt): block-local
// inclusive scan + one atomicAdd per block (segment order is arbitrary).
__global__ void k_base(const int* __restrict__ cnt, int* __restrict__ base,
                       int* __restrict__ cursor, int* __restrict__ total, int n)
{
    __shared__ int sd[256];
    __shared__ int sbase;
    const int tid = threadIdx.x;
    const int gid = blockIdx.x * 256 + tid;
    int c = (gid < n) ? cnt[gid] : 0;
    sd[tid] = c;
    __syncthreads();
    for (int off = 1; off < 256; off <<= 1) {
        int v = (tid >= off) ? sd[tid - off] : 0;
        __syncthreads();
        sd[tid] += v;
        __syncthreads();
    }
    if (tid == 255) sbase = atomicAdd(total, sd[255]);
    __syncthreads();
    if (gid < n) {
        int b = sbase + sd[tid] - c;
        base[gid]   = b;
        cursor[gid] = b;
    }
}

// Scatter src-id into the dst node's CSR segment (order within segment arbitrary).
__global__ void k_fill(const int* __restrict__ src, const int* __restrict__ dst,
                       int* __restrict__ cursor, int* __restrict__ col)
{
    int i = blockIdx.x * blockDim.x + threadIdx.x;
    if (i >= NE) return;
    int pos = atomicAdd(&cursor[dst[i]], 1);
    col[pos] = src[i];
}

// One wave per dst node; 64-edge batches, 4x-unrolled broadcast inner loop
// (4 independent Wh row loads in flight). Lane owns 2 output dims.
__global__ void k_agg(const int* __restrict__ base, const int* __restrict__ cnt,
                      const int* __restrict__ col, const float* __restrict__ ssrc,
                      const float* __restrict__ sdst_arr, const bf16* __restrict__ Whs,
                      const float* __restrict__ addend, float* __restrict__ out, int n)
{
    const int gw   = (int)((blockIdx.x * blockDim.x + threadIdx.x) >> 6);
    const int lane = threadIdx.x & 63;
    if (gw >= n) return;
    const int b = base[gw], c = cnt[gw];
    const float sdv = sdst_arr[gw];

    float ax = 0.f, ay = 0.f, dpart = 0.f;
    for (int t0 = 0; t0 < c; t0 += 64) {
        const int rem = c - t0;
        const int k = rem < 64 ? rem : 64;
        int myc = 0; float myex = 0.f;     // inactive lanes contribute exactly 0
        if (lane < k) {
            myc = col[b + t0 + lane];
            float e = ssrc[myc] + sdv;
            e = (e >= 0.f) ? e : 0.01f * e;
            myex = __expf(fminf(e, 30.f));
        }
        dpart += myex;
        const int kk = (k + 3) & ~3;
        for (int j = 0; j < kk; j += 4) {
            int   s0 = __shfl(myc, j),     s1v = __shfl(myc, j + 1);
            int   s2v = __shfl(myc, j + 2), s3v = __shfl(myc, j + 3);
            float e0 = __shfl(myex, j),     e1 = __shfl(myex, j + 1);
            float e2 = __shfl(myex, j + 2), e3 = __shfl(myex, j + 3);
            __hip_bfloat162 w0 = *(const __hip_bfloat162*)(Whs + (size_t)s0 * D + 2 * lane);
            __hip_bfloat162 w1 = *(const __hip_bfloat162*)(Whs + (size_t)s1v * D + 2 * lane);
            __hip_bfloat162 w2 = *(const __hip_bfloat162*)(Whs + (size_t)s2v * D + 2 * lane);
            __hip_bfloat162 w3 = *(const __hip_bfloat162*)(Whs + (size_t)s3v * D + 2 * lane);
            ax += e0 * b2f(w0.x) + e1 * b2f(w1.x) + e2 * b2f(w2.x) + e3 * b2f(w3.x);
            ay += e0 * b2f(w0.y) + e1 * b2f(w1.y) + e2 * b2f(w2.y) + e3 * b2f(w3.y);
        }
    }
    float denom = dpart;
#pragma unroll
    for (int off = 32; off; off >>= 1) denom += __shfl_xor(denom, off);
    const float inv = (c > 0) ? 1.f / denom : 0.f;
    ax *= inv; ay *= inv;

    size_t idx = (size_t)gw * D + 2 * lane;
    if (addend) { ax += addend[idx]; ay += addend[idx + 1]; }
    *(float2*)(out + idx) = make_float2(ax, ay);
}

extern "C" void kernel_launch(void* const* d_in, const int* in_sizes, int n_in,
                              void* d_out, int out_size, void* d_ws, size_t ws_size,
                              hipStream_t stream)
{
    const float* feat_drug = (const float*)d_in[0];
    const float* feat_dis  = (const float*)d_in[1];
    const int*   src_ind   = (const int*)d_in[2];
    const int*   dst_ind   = (const int*)d_in[3];
    const int*   src_rev   = (const int*)d_in[4];
    const int*   dst_rev   = (const int*)d_in[5];
    const int*   src_dd    = (const int*)d_in[6];
    const int*   dst_dd    = (const int*)d_in[7];
    const float* W_ind     = (const float*)d_in[8];
    const float* b_ind     = (const float*)d_in[9];
    const float* W_rev     = (const float*)d_in[10];
    const float* b_rev     = (const float*)d_in[11];
    const float* W_dd      = (const float*)d_in[12];
    const float* b_dd      = (const float*)d_in[13];
    const float* a_ind     = (const float*)d_in[14];
    const float* a_rev     = (const float*)d_in[15];
    const float* a_dd      = (const float*)d_in[16];

    float* out_drug = (float*)d_out;                        // [N_DRUG, D] f32
    float* out_dis  = (float*)d_out + (size_t)N_DRUG * D;   // [N_DIS, D]  f32

    char* ws = (char*)d_ws;
    size_t off = 0;
    auto alloc = [&](size_t bytes) -> void* {
        void* p = ws + off;
        off += (bytes + 255) & ~(size_t)255;
        return p;
    };

    // total ws usage ~34 MB
    bf16* Wh_ind = (bf16*)alloc(sizeof(bf16) * (size_t)N_DRUG * D);
    bf16* Wh_rev = (bf16*)alloc(sizeof(bf16) * (size_t)N_DIS * D);
    bf16* Wh_dd  = (bf16*)alloc(sizeof(bf16) * (size_t)N_DIS * D);

    float* s_src_ind = (float*)alloc(sizeof(float) * N_DRUG);  // Wh_ind . a_ind[:D]
    float* s_dst_rev = (float*)alloc(sizeof(float) * N_DRUG);  // Wh_ind . a_rev[D:]
    float* s_src_rev = (float*)alloc(sizeof(float) * N_DIS);   // Wh_rev . a_rev[:D]
    float* s_dst_ind = (float*)alloc(sizeof(float) * N_DIS);   // Wh_rev . a_ind[D:]
    float* s_src_dd  = (float*)alloc(sizeof(float) * N_DIS);   // Wh_dd  . a_dd[:D]
    float* s_dst_dd  = (float*)alloc(sizeof(float) * N_DIS);   // Wh_dd  . a_dd[D:]

    int* col_ind = (int*)alloc(sizeof(int) * NE);
    int* col_rev = (int*)alloc(sizeof(int) * NE);
    int* col_dd  = (int*)alloc(sizeof(int) * NE);

    int* base_ind   = (int*)alloc(sizeof(int) * N_DIS);
    int* cursor_ind = (int*)alloc(sizeof(int) * N_DIS);
    int* base_rev   = (int*)alloc(sizeof(int) * N_DRUG);
    int* cursor_rev = (int*)alloc(sizeof(int) * N_DRUG);
    int* base_dd    = (int*)alloc(sizeof(int) * N_DIS);
    int* cursor_dd  = (int*)alloc(sizeof(int) * N_DIS);

    // zero region: cnt_ind | cnt_dd | cnt_rev | totals(4)
    const size_t nzero = (size_t)N_DIS + N_DIS + N_DRUG + 4;
    int* zr = (int*)alloc(sizeof(int) * nzero);
    int* cnt_ind = zr;
    int* cnt_dd  = zr + N_DIS;
    int* cnt_rev = zr + 2 * N_DIS;
    int* totals  = zr + 2 * N_DIS + N_DRUG;  // [ind, rev, dd, pad]

    hipMemsetAsync(zr, 0, sizeof(int) * nzero, stream);

    // --- MFMA projections + per-node attention scalars ---
    k_gemm_mfma<<<(N_DRUG + 63) / 64, 256, 0, stream>>>(feat_drug, N_DRUG, W_ind, b_ind,
                                                        a_ind, a_rev + D, Wh_ind,
                                                        s_src_ind, s_dst_rev);
    k_gemm_mfma<<<(N_DIS + 63) / 64, 256, 0, stream>>>(feat_dis, N_DIS, W_rev, b_rev,
                                                       a_rev, a_ind + D, Wh_rev,
                                                       s_src_rev, s_dst_ind);
    k_gemm_mfma<<<(N_DIS + 63) / 64, 256, 0, stream>>>(feat_dis, N_DIS, W_dd, b_dd,
                                                       a_dd, a_dd + D, Wh_dd,
                                                       s_src_dd, s_dst_dd);

    const int EB = (NE + 255) / 256;

    // --- CSR build: histogram -> base alloc -> fill ---
    k_hist<<<EB, 256, 0, stream>>>(dst_ind, cnt_ind);
    k_hist<<<EB, 256, 0, stream>>>(dst_rev, cnt_rev);
    k_hist<<<EB, 256, 0, stream>>>(dst_dd, cnt_dd);

    k_base<<<(N_DIS + 255) / 256, 256, 0, stream>>>(cnt_ind, base_ind, cursor_ind, &totals[0], N_DIS);
    k_base<<<(N_DRUG + 255) / 256, 256, 0, stream>>>(cnt_rev, base_rev, cursor_rev, &totals[1], N_DRUG);
    k_base<<<(N_DIS + 255) / 256, 256, 0, stream>>>(cnt_dd, base_dd, cursor_dd, &totals[2], N_DIS);

    k_fill<<<EB, 256, 0, stream>>>(src_ind, dst_ind, cursor_ind, col_ind);
    k_fill<<<EB, 256, 0, stream>>>(src_rev, dst_rev, cursor_rev, col_rev);
    k_fill<<<EB, 256, 0, stream>>>(src_dd, dst_dd, cursor_dd, col_dd);

    // --- gather-based softmax aggregation (one wave per dst node) ---
    // indication -> out_dis (f32)
    k_agg<<<(N_DIS + 3) / 4, 256, 0, stream>>>(base_ind, cnt_ind, col_ind,
                                               s_src_ind, s_dst_ind, Wh_ind,
                                               nullptr, out_dis, N_DIS);
    // dd, adding out_dis in place -> final h_dis
    k_agg<<<(N_DIS + 3) / 4, 256, 0, stream>>>(base_dd, cnt_dd, col_dd,
                                               s_src_dd, s_dst_dd, Wh_dd,
                                               out_dis, out_dis, N_DIS);
    // rev_indication -> h_drug
    k_agg<<<(N_DRUG + 3) / 4, 256, 0, stream>>>(base_rev, cnt_rev, col_rev,
                                                s_src_rev, s_dst_rev, Wh_rev,
                                                nullptr, out_drug, N_DRUG);
}